// Round 1
// baseline (3879.005 us; speedup 1.0000x reference)
//
#include <hip/hip_runtime.h>

// StockLSTM: 2-layer LSTM (B=4096, T=256, I=5, H=64) + FC(64->25), fp32.
// Fully fused persistent-block kernel: each block owns BB=8 batch rows for the
// entire time loop. Weights stationary in registers (gate rows split across
// thread pairs). fp32 vector math throughout (no fp32 MFMA on CDNA4).

#define BB   8      // batch rows per block
#define TT   256    // timesteps
#define II   5      // input dim
#define HH   64     // hidden dim
#define GG   256    // 4*H gates
#define OO   25     // fc out
#define NTHR 512    // threads per block (= GG*2 halves = BB*HH)

__device__ __forceinline__ float frcp(float x) { return __builtin_amdgcn_rcpf(x); }

__device__ __forceinline__ float fsig(float x) {
    x = fminf(fmaxf(x, -30.f), 30.f);
    return frcp(1.f + __expf(-x));
}
__device__ __forceinline__ float ftanhf(float x) {
    x = fminf(fmaxf(x, -15.f), 15.f);
    float e = __expf(2.f * x);
    return (e - 1.f) * frcp(e + 1.f);
}

__global__ __launch_bounds__(NTHR)
void lstm_fused(const float* __restrict__ x,
                const float* __restrict__ Wih0, const float* __restrict__ Whh0,
                const float* __restrict__ bih0, const float* __restrict__ bhh0,
                const float* __restrict__ Wih1, const float* __restrict__ Whh1,
                const float* __restrict__ bih1, const float* __restrict__ bhh1,
                const float* __restrict__ Wfc,  const float* __restrict__ bfc,
                float* __restrict__ out)
{
    __shared__ float xs[BB * TT * II];   // 40 KB: x tile for this block
    __shared__ float h1s[BB * HH];       // 2 KB
    __shared__ float h2s[BB * HH];       // 2 KB
    __shared__ float part[BB * GG * 2];  // 16 KB: gate partials (2 halves)

    const int tid  = threadIdx.x;
    const int g    = tid >> 1;   // gate-role: gate row 0..255
    const int half = tid & 1;    // gate-role: which K-half
    const int cb   = tid >> 6;   // cell-role: batch row 0..7
    const int cj   = tid & 63;   // cell-role: hidden unit 0..63

    // ---- preload x tile (coalesced float4: 2560 float4 / 512 thr = 5 each) ----
    {
        const float4* src = reinterpret_cast<const float4*>(
            x + (size_t)blockIdx.x * (BB * TT * II));
        float4* dst = reinterpret_cast<float4*>(xs);
        #pragma unroll
        for (int i = 0; i < (BB * TT * II / 4) / NTHR; ++i)
            dst[tid + i * NTHR] = src[tid + i * NTHR];
    }
    h1s[tid] = 0.f;   // BB*HH == NTHR exactly
    h2s[tid] = 0.f;

    // ---- weights -> registers (stationary across the whole time loop) ----
    // half 0: Wih0 row (5) + Whh0 row [0:32) + Wih1 row (64) + biases
    // half 1:             Whh0 row [32:64) + Whh1 row (64)
    float wx[II];
    float wh0[32];
    float w1[HH];
    float b0 = 0.f, b1 = 0.f;
    {
        const float* pw1 = half ? (Whh1 + g * HH) : (Wih1 + g * HH);
        #pragma unroll
        for (int k = 0; k < HH; ++k) w1[k] = pw1[k];
        const float* pw0 = Whh0 + g * HH + half * 32;
        #pragma unroll
        for (int k = 0; k < 32; ++k) wh0[k] = pw0[k];
        if (!half) {
            #pragma unroll
            for (int i = 0; i < II; ++i) wx[i] = Wih0[g * II + i];
            b0 = bih0[g] + bhh0[g];
            b1 = bih1[g] + bhh1[g];
        } else {
            #pragma unroll
            for (int i = 0; i < II; ++i) wx[i] = 0.f;
        }
    }
    float c1 = 0.f, c2 = 0.f;
    __syncthreads();

    for (int t = 0; t < TT; ++t) {
        // ---- Phase A: layer-1 gate partials ----
        #pragma unroll
        for (int bb = 0; bb < BB; ++bb) {
            const float* xv = xs + bb * (TT * II) + t * II;
            float acc = b0;
            #pragma unroll
            for (int i = 0; i < II; ++i) acc += wx[i] * xv[i];   // wx==0 for half1
            const float4* h4 = reinterpret_cast<const float4*>(h1s + bb * HH + half * 32);
            #pragma unroll
            for (int kk = 0; kk < 8; ++kk) {
                float4 v = h4[kk];
                acc += wh0[4*kk+0]*v.x + wh0[4*kk+1]*v.y
                     + wh0[4*kk+2]*v.z + wh0[4*kk+3]*v.w;
            }
            part[bb * (GG * 2) + tid] = acc;
        }
        __syncthreads();

        // ---- Phase B: layer-1 cell update (gate order i,f,g,o) ----
        {
            const float2* p2 = reinterpret_cast<const float2*>(part + cb * (GG * 2));
            float2 pi = p2[0 * HH + cj];
            float2 pf = p2[1 * HH + cj];
            float2 pg = p2[2 * HH + cj];
            float2 po = p2[3 * HH + cj];
            float gi = fsig(pi.x + pi.y);
            float gf = fsig(pf.x + pf.y);
            float gz = ftanhf(pg.x + pg.y);
            float go = fsig(po.x + po.y);
            c1 = gf * c1 + gi * gz;
            h1s[cb * HH + cj] = go * ftanhf(c1);
        }
        __syncthreads();

        // ---- Phase C: layer-2 gate partials (K = [h1 ; h2]) ----
        #pragma unroll
        for (int bb = 0; bb < BB; ++bb) {
            const float* src = half ? (h2s + bb * HH) : (h1s + bb * HH);
            const float4* s4 = reinterpret_cast<const float4*>(src);
            float acc = b1;
            #pragma unroll
            for (int kk = 0; kk < 16; ++kk) {
                float4 v = s4[kk];
                acc += w1[4*kk+0]*v.x + w1[4*kk+1]*v.y
                     + w1[4*kk+2]*v.z + w1[4*kk+3]*v.w;
            }
            part[bb * (GG * 2) + tid] = acc;
        }
        __syncthreads();

        // ---- Phase D: layer-2 cell update ----
        {
            const float2* p2 = reinterpret_cast<const float2*>(part + cb * (GG * 2));
            float2 pi = p2[0 * HH + cj];
            float2 pf = p2[1 * HH + cj];
            float2 pg = p2[2 * HH + cj];
            float2 po = p2[3 * HH + cj];
            float gi = fsig(pi.x + pi.y);
            float gf = fsig(pf.x + pf.y);
            float gz = ftanhf(pg.x + pg.y);
            float go = fsig(po.x + po.y);
            c2 = gf * c2 + gi * gz;
            h2s[cb * HH + cj] = go * ftanhf(c2);
        }
        __syncthreads();
    }

    // ---- FC epilogue: out = h2[:,T-1,:] @ Wfc^T + bfc ----
    if (tid < BB * OO) {
        int bb = tid / OO, o = tid % OO;
        float acc = bfc[o];
        const float* wrow = Wfc + o * HH;
        const float* hrow = h2s + bb * HH;
        #pragma unroll
        for (int j = 0; j < HH; ++j) acc += wrow[j] * hrow[j];
        out[((size_t)blockIdx.x * BB + bb) * OO + o] = acc;
    }
}

extern "C" void kernel_launch(void* const* d_in, const int* in_sizes, int n_in,
                              void* d_out, int out_size, void* d_ws, size_t ws_size,
                              hipStream_t stream) {
    const float* x    = (const float*)d_in[0];
    const float* Wih0 = (const float*)d_in[1];
    const float* Whh0 = (const float*)d_in[2];
    const float* bih0 = (const float*)d_in[3];
    const float* bhh0 = (const float*)d_in[4];
    const float* Wih1 = (const float*)d_in[5];
    const float* Whh1 = (const float*)d_in[6];
    const float* bih1 = (const float*)d_in[7];
    const float* bhh1 = (const float*)d_in[8];
    const float* Wfc  = (const float*)d_in[9];
    const float* bfc  = (const float*)d_in[10];
    float* out = (float*)d_out;

    const int B = 4096;
    dim3 grid(B / BB), block(NTHR);
    lstm_fused<<<grid, block, 0, stream>>>(x, Wih0, Whh0, bih0, bhh0,
                                           Wih1, Whh1, bih1, bhh1,
                                           Wfc, bfc, out);
}

// Round 3
// 705.863 us; speedup vs baseline: 5.4954x; 5.4954x over previous
//
#include <hip/hip_runtime.h>

// StockLSTM via bf16 hi/lo split MFMA (3-term) on 16x16x32 tiles.
// Block = 16 batch rows, 512 threads (8 waves). Wave w computes gates
// [32w, 32w+32) for both layers; weights live pre-split in registers as
// B-fragments. h1/h2 in LDS as bf16 hi/lo; gates via fp32 LDS buffer.

#define TT   256
#define II   5
#define HH   64
#define OO   25
#define MT   16         // batch rows per block
#define NTHR 512
#define SG   258        // gate LDS row stride (floats) -> 2-way bank patterns
#define XR   325        // xs row stride (floats) = 64*5 + 5 (bank skew)
#define HR   72         // h row stride (ushorts) = 64 + 8 pad (16B aligned)

typedef __attribute__((ext_vector_type(8))) short  short8;
typedef __attribute__((ext_vector_type(4))) float  floatx4;

#define MFMA(a, b, c) __builtin_amdgcn_mfma_f32_16x16x32_bf16(a, b, c, 0, 0, 0)

__device__ __forceinline__ float frcp(float x) { return __builtin_amdgcn_rcpf(x); }
__device__ __forceinline__ float fsig(float x) {
    x = fminf(fmaxf(x, -30.f), 30.f);
    return frcp(1.f + __expf(-x));
}
__device__ __forceinline__ float ftanhf(float x) {
    x = fminf(fmaxf(x, -15.f), 15.f);
    float e = __expf(2.f * x);
    return (e - 1.f) * frcp(e + 1.f);
}
__device__ __forceinline__ unsigned short bf16_rne(float f) {
    unsigned int u = __builtin_bit_cast(unsigned int, f);
    u += 0x7FFFu + ((u >> 16) & 1u);
    return (unsigned short)(u >> 16);
}
__device__ __forceinline__ float bf16_f(unsigned short h) {
    unsigned int u = ((unsigned int)h) << 16;
    return __builtin_bit_cast(float, u);
}
struct HiLo { short hi, lo; };
__device__ __forceinline__ HiLo split2(float v) {
    HiLo r;
    unsigned short h = bf16_rne(v);
    r.hi = (short)h;
    r.lo = (short)bf16_rne(v - bf16_f(h));
    return r;
}

__global__ __launch_bounds__(NTHR, 2)
void lstm_mfma(const float* __restrict__ x,
               const float* __restrict__ Wih0, const float* __restrict__ Whh0,
               const float* __restrict__ bih0, const float* __restrict__ bhh0,
               const float* __restrict__ Wih1, const float* __restrict__ Whh1,
               const float* __restrict__ bih1, const float* __restrict__ bhh1,
               const float* __restrict__ Wfc,  const float* __restrict__ bfc,
               float* __restrict__ out)
{
    __shared__ __align__(16) float          xs[MT * XR];        // 20.8 KB (64-step x chunk)
    __shared__ __align__(16) float          gate_s[MT * SG];    // 16.5 KB
    __shared__ __align__(16) unsigned short h1hi_s[MT * HR];    // 2.25 KB
    __shared__ __align__(16) unsigned short h1lo_s[MT * HR];
    __shared__ __align__(16) unsigned short h2hi_s[MT * HR];
    __shared__ __align__(16) unsigned short h2lo_s[MT * HR];
    __shared__ __align__(16) float          h2f_s[MT * HH];     // 4 KB (final h2)

    const int tid  = threadIdx.x;
    const int wave = tid >> 6;
    const int lane = tid & 63;
    const int col  = lane & 15;   // A-frag m / B-frag n / C col
    const int quad = lane >> 4;   // k-subrange selector / C row group

    // ---------------- B-fragment (weight) preload, hi/lo split ----------------
    // B layout: lane holds B[k = quad*8 + j][n = tilebase + col], j = 0..7.
    short8 Bxh[2], Bxl[2];          // L1 x-chunk (k<5 real, rest 0)
    short8 B1h[2][2], B1l[2][2];    // L1 h chunks [chunk][tile]
    short8 B2h[4][2], B2l[4][2];    // L2 chunks: 0,1 = h1 (Wih1), 2,3 = h2 (Whh1)
    float  bias1[2], bias2[2];

    #pragma unroll
    for (int tl = 0; tl < 2; ++tl) {
        const int n = wave * 32 + tl * 16 + col;
        bias1[tl] = bih0[n] + bhh0[n];
        bias2[tl] = bih1[n] + bhh1[n];
        #pragma unroll
        for (int j = 0; j < 8; ++j) {
            int k = quad * 8 + j;
            float w = (k < II) ? Wih0[n * II + k] : 0.f;
            HiLo s = split2(w);
            Bxh[tl][j] = s.hi; Bxl[tl][j] = s.lo;
        }
        #pragma unroll
        for (int c = 0; c < 2; ++c)
            #pragma unroll
            for (int j = 0; j < 8; ++j) {
                int k = c * 32 + quad * 8 + j;
                HiLo s = split2(Whh0[n * HH + k]);
                B1h[c][tl][j] = s.hi; B1l[c][tl][j] = s.lo;
            }
        #pragma unroll
        for (int c = 0; c < 4; ++c)
            #pragma unroll
            for (int j = 0; j < 8; ++j) {
                int k = c * 32 + quad * 8 + j;
                float w = (k < HH) ? Wih1[n * HH + k] : Whh1[n * HH + (k - HH)];
                HiLo s = split2(w);
                B2h[c][tl][j] = s.hi; B2l[c][tl][j] = s.lo;
            }
    }

    // ---------------- zero h state ----------------
    for (int i = tid; i < MT * HR / 2; i += NTHR) {
        ((unsigned int*)h1hi_s)[i] = 0u;
        ((unsigned int*)h1lo_s)[i] = 0u;
        ((unsigned int*)h2hi_s)[i] = 0u;
        ((unsigned int*)h2lo_s)[i] = 0u;
    }

    float c1a = 0.f, c1b = 0.f, c2a = 0.f, c2b = 0.f;
    const int  ub  = tid >> 5;          // update role: batch row
    const int  ujj = (tid & 31) << 1;   // update role: j, j+1
    const bool is_tanh = ((wave >> 1) == 2);

    __syncthreads();

    for (int t = 0; t < TT; ++t) {
        // ---- refill 64-step x chunk ----
        if ((t & 63) == 0) {
            const int seg = tid >> 5, li = tid & 31;
            const float* src = x + ((size_t)(blockIdx.x * MT + seg) * TT + t) * II;
            float* dst = xs + seg * XR;
            #pragma unroll
            for (int i = 0; i < 10; ++i)
                dst[li + i * 32] = src[li + i * 32];
            __syncthreads();
        }
        const int dt = t & 63;

        // ================= Phase A: layer-1 gates =================
        short8 Axh = {0,0,0,0,0,0,0,0}, Axl = {0,0,0,0,0,0,0,0};
        if (quad == 0) {
            const float* xv = xs + col * XR + dt * II;
            #pragma unroll
            for (int i = 0; i < II; ++i) {
                HiLo s = split2(xv[i]);
                Axh[i] = s.hi; Axl[i] = s.lo;
            }
        }
        short8 A1h[2], A1l[2];
        #pragma unroll
        for (int c = 0; c < 2; ++c) {
            const int off = col * HR + c * 32 + quad * 8;
            A1h[c] = *reinterpret_cast<const short8*>(h1hi_s + off);
            A1l[c] = *reinterpret_cast<const short8*>(h1lo_s + off);
        }
        #pragma unroll
        for (int tl = 0; tl < 2; ++tl) {
            floatx4 acc = {bias1[tl], bias1[tl], bias1[tl], bias1[tl]};
            acc = MFMA(Axh, Bxh[tl], acc);
            acc = MFMA(Axh, Bxl[tl], acc);
            acc = MFMA(Axl, Bxh[tl], acc);
            #pragma unroll
            for (int c = 0; c < 2; ++c) {
                acc = MFMA(A1h[c], B1h[c][tl], acc);
                acc = MFMA(A1h[c], B1l[c][tl], acc);
                acc = MFMA(A1l[c], B1h[c][tl], acc);
            }
            #pragma unroll
            for (int r = 0; r < 4; ++r) {
                float v = acc[r];
                v = is_tanh ? ftanhf(v) : fsig(v);
                gate_s[(quad * 4 + r) * SG + wave * 32 + tl * 16 + col] = v;
            }
        }
        __syncthreads();

        // ================= update 1 =================
        {
            const float* gb = gate_s + ub * SG + ujj;
            float2 gi = *(const float2*)(gb);
            float2 gf = *(const float2*)(gb + 64);
            float2 gg = *(const float2*)(gb + 128);
            float2 go = *(const float2*)(gb + 192);
            c1a = gf.x * c1a + gi.x * gg.x;
            c1b = gf.y * c1b + gi.y * gg.y;
            float h0 = go.x * ftanhf(c1a);
            float h1v = go.y * ftanhf(c1b);
            unsigned short h0h = bf16_rne(h0), h1h = bf16_rne(h1v);
            unsigned short h0l = bf16_rne(h0 - bf16_f(h0h));
            unsigned short h1l = bf16_rne(h1v - bf16_f(h1h));
            const int ui = ub * (HR / 2) + (ujj >> 1);
            ((unsigned int*)h1hi_s)[ui] = (unsigned int)h0h | ((unsigned int)h1h << 16);
            ((unsigned int*)h1lo_s)[ui] = (unsigned int)h0l | ((unsigned int)h1l << 16);
        }
        __syncthreads();

        // ================= Phase C: layer-2 gates =================
        short8 C1h[2], C1l[2], C2h[2], C2l[2];
        #pragma unroll
        for (int c = 0; c < 2; ++c) {
            const int off = col * HR + c * 32 + quad * 8;
            C1h[c] = *reinterpret_cast<const short8*>(h1hi_s + off);
            C1l[c] = *reinterpret_cast<const short8*>(h1lo_s + off);
            C2h[c] = *reinterpret_cast<const short8*>(h2hi_s + off);
            C2l[c] = *reinterpret_cast<const short8*>(h2lo_s + off);
        }
        #pragma unroll
        for (int tl = 0; tl < 2; ++tl) {
            floatx4 acc = {bias2[tl], bias2[tl], bias2[tl], bias2[tl]};
            #pragma unroll
            for (int c = 0; c < 2; ++c) {
                acc = MFMA(C1h[c], B2h[c][tl], acc);
                acc = MFMA(C1h[c], B2l[c][tl], acc);
                acc = MFMA(C1l[c], B2h[c][tl], acc);
            }
            #pragma unroll
            for (int c = 0; c < 2; ++c) {
                acc = MFMA(C2h[c], B2h[c + 2][tl], acc);
                acc = MFMA(C2h[c], B2l[c + 2][tl], acc);
                acc = MFMA(C2l[c], B2h[c + 2][tl], acc);
            }
            #pragma unroll
            for (int r = 0; r < 4; ++r) {
                float v = acc[r];
                v = is_tanh ? ftanhf(v) : fsig(v);
                gate_s[(quad * 4 + r) * SG + wave * 32 + tl * 16 + col] = v;
            }
        }
        __syncthreads();

        // ================= update 2 =================
        {
            const float* gb = gate_s + ub * SG + ujj;
            float2 gi = *(const float2*)(gb);
            float2 gf = *(const float2*)(gb + 64);
            float2 gg = *(const float2*)(gb + 128);
            float2 go = *(const float2*)(gb + 192);
            c2a = gf.x * c2a + gi.x * gg.x;
            c2b = gf.y * c2b + gi.y * gg.y;
            float h0 = go.x * ftanhf(c2a);
            float h1v = go.y * ftanhf(c2b);
            unsigned short h0h = bf16_rne(h0), h1h = bf16_rne(h1v);
            unsigned short h0l = bf16_rne(h0 - bf16_f(h0h));
            unsigned short h1l = bf16_rne(h1v - bf16_f(h1h));
            const int ui = ub * (HR / 2) + (ujj >> 1);
            ((unsigned int*)h2hi_s)[ui] = (unsigned int)h0h | ((unsigned int)h1h << 16);
            ((unsigned int*)h2lo_s)[ui] = (unsigned int)h0l | ((unsigned int)h1l << 16);
            if (t == TT - 1) {
                *(float2*)(h2f_s + ub * HH + ujj) = make_float2(h0, h1v);
            }
        }
        __syncthreads();
    }

    // ================= FC epilogue =================
    if (tid < MT * OO) {
        const int b = tid / OO, o = tid % OO;
        float acc = bfc[o];
        const float* wr = Wfc + o * HH;
        const float* hr = h2f_s + b * HH;
        #pragma unroll
        for (int j = 0; j < HH; ++j) acc += wr[j] * hr[j];
        out[((size_t)blockIdx.x * MT + b) * OO + o] = acc;
    }
}

extern "C" void kernel_launch(void* const* d_in, const int* in_sizes, int n_in,
                              void* d_out, int out_size, void* d_ws, size_t ws_size,
                              hipStream_t stream) {
    const float* x    = (const float*)d_in[0];
    const float* Wih0 = (const float*)d_in[1];
    const float* Whh0 = (const float*)d_in[2];
    const float* bih0 = (const float*)d_in[3];
    const float* bhh0 = (const float*)d_in[4];
    const float* Wih1 = (const float*)d_in[5];
    const float* Whh1 = (const float*)d_in[6];
    const float* bih1 = (const float*)d_in[7];
    const float* bhh1 = (const float*)d_in[8];
    const float* Wfc  = (const float*)d_in[9];
    const float* bfc  = (const float*)d_in[10];
    float* out = (float*)d_out;

    dim3 grid(4096 / MT), block(NTHR);
    lstm_mfma<<<grid, block, 0, stream>>>(x, Wih0, Whh0, bih0, bhh0,
                                          Wih1, Whh1, bih1, bhh1,
                                          Wfc, bfc, out);
}

// Round 4
// 464.935 us; speedup vs baseline: 8.3431x; 1.5182x over previous
//
#include <hip/hip_runtime.h>

// StockLSTM: A=weights / B=state MFMA layout so gate nonlinearity + cell
// update are in-register. 1024-thread blocks (16 waves, 4/SIMD), wave w owns
// hidden units j in [4w,4w+4) across all 4 gate groups; 2 barriers/step with
// t-parity double-buffered h state. bf16 hi/lo 3-term MFMA; x-term in fp32 VALU.

#define TT   256
#define II   5
#define HH   64
#define OO   25
#define MT   16        // batch rows per block (MFMA n-dim)
#define NTHR 1024
#define XR   325       // xs row stride (floats): 320 + 5 skew
#define HR   72        // h row stride (ushorts): 64 + 8 pad (16B aligned)
#define HF   65        // h2f row stride (floats)

typedef __attribute__((ext_vector_type(8))) short  short8;
typedef __attribute__((ext_vector_type(4))) float  floatx4;

#define MFMA(a, b, c) __builtin_amdgcn_mfma_f32_16x16x32_bf16(a, b, c, 0, 0, 0)

__device__ __forceinline__ float frcp(float x) { return __builtin_amdgcn_rcpf(x); }
// clamp-free: x->+inf => exp2->inf => rcp->0 => 1 ; x->-inf => 0+1 => 1 => ... safe
__device__ __forceinline__ float fsig(float x) {
    return frcp(1.f + __builtin_amdgcn_exp2f(x * -1.44269504f));
}
__device__ __forceinline__ float ftanhf(float x) {
    return 1.f - 2.f * frcp(1.f + __builtin_amdgcn_exp2f(x * 2.88539008f));
}
__device__ __forceinline__ unsigned short bf16_rne(float f) {
    unsigned int u = __builtin_bit_cast(unsigned int, f);
    u += 0x7FFFu + ((u >> 16) & 1u);
    return (unsigned short)(u >> 16);
}
__device__ __forceinline__ float bf16_f(unsigned short h) {
    unsigned int u = ((unsigned int)h) << 16;
    return __builtin_bit_cast(float, u);
}
struct HiLo { short hi, lo; };
__device__ __forceinline__ HiLo split2(float v) {
    HiLo r;
    unsigned short h = bf16_rne(v);
    r.hi = (short)h;
    r.lo = (short)bf16_rne(v - bf16_f(h));
    return r;
}

__global__ __launch_bounds__(NTHR)
void lstm_mfma2(const float* __restrict__ x,
                const float* __restrict__ Wih0, const float* __restrict__ Whh0,
                const float* __restrict__ bih0, const float* __restrict__ bhh0,
                const float* __restrict__ Wih1, const float* __restrict__ Whh1,
                const float* __restrict__ bih1, const float* __restrict__ bhh1,
                const float* __restrict__ Wfc,  const float* __restrict__ bfc,
                float* __restrict__ out)
{
    __shared__ __align__(16) float          xs[MT * XR];          // 20.8 KB
    __shared__ __align__(16) unsigned short h1hi[2][MT * HR];     // 4.6 KB each pair
    __shared__ __align__(16) unsigned short h1lo[2][MT * HR];
    __shared__ __align__(16) unsigned short h2hi[2][MT * HR];
    __shared__ __align__(16) unsigned short h2lo[2][MT * HR];
    __shared__ __align__(16) float          h2f[MT * HF];         // 4.2 KB

    const int tid   = threadIdx.x;
    const int w     = tid >> 6;       // wave 0..15
    const int lane  = tid & 63;
    const int b     = lane & 15;      // batch col (B n-dim / C col)
    const int q     = lane >> 4;      // k-slice selector / C row-quad
    const int jmine = 4 * w + q;      // this lane's hidden unit
    const int hw_off = b * HR + jmine;

    // ---------------- A-fragment (weight) preload ----------------
    // Tile row m in [0,16): gate group = m&3, hidden j = 4w + (m>>2).
    // A layout: lane holds A[m = lane&15][k = q*8 + jj].
    short8 A1h[2], A1l[2];   // Whh0 k-chunks
    short8 A2h[4], A2l[4];   // chunks 0,1: Wih1 (h1 side); 2,3: Whh1 (h2 side)
    {
        const int rr = lane & 15;
        const int g  = (rr & 3) * 64 + 4 * w + (rr >> 2);
        #pragma unroll
        for (int c = 0; c < 2; ++c)
            #pragma unroll
            for (int jj = 0; jj < 8; ++jj) {
                HiLo s = split2(Whh0[g * HH + c * 32 + q * 8 + jj]);
                A1h[c][jj] = s.hi; A1l[c][jj] = s.lo;
            }
        #pragma unroll
        for (int c = 0; c < 4; ++c)
            #pragma unroll
            for (int jj = 0; jj < 8; ++jj) {
                const int k = c * 32 + q * 8 + jj;
                float wv = (k < HH) ? Wih1[g * HH + k] : Whh1[g * HH + (k - HH)];
                HiLo s = split2(wv);
                A2h[c][jj] = s.hi; A2l[c][jj] = s.lo;
            }
    }
    // x weights (exact fp32 VALU path) + biases, indexed by acc reg r:
    // acc[r] <-> gate row r*64 + jmine.
    float Wx[4][II], bias1[4], bias2[4];
    #pragma unroll
    for (int r = 0; r < 4; ++r) {
        const int g = r * 64 + jmine;
        bias1[r] = bih0[g] + bhh0[g];
        bias2[r] = bih1[g] + bhh1[g];
        #pragma unroll
        for (int i = 0; i < II; ++i) Wx[r][i] = Wih0[g * II + i];
    }

    // ---------------- zero h state (both parities) ----------------
    {
        unsigned int* z1 = (unsigned int*)h1hi;
        unsigned int* z2 = (unsigned int*)h1lo;
        unsigned int* z3 = (unsigned int*)h2hi;
        unsigned int* z4 = (unsigned int*)h2lo;
        for (int i = tid; i < MT * HR; i += NTHR) {  // MT*HR uints = full [2][] array
            z1[i] = 0u; z2[i] = 0u; z3[i] = 0u; z4[i] = 0u;
        }
    }
    float c1 = 0.f, c2 = 0.f;
    __syncthreads();

    for (int t = 0; t < TT; ++t) {
        // ---- refill 64-step x chunk (wave w loads batch row w) ----
        if ((t & 63) == 0) {
            const float* src = x + ((size_t)(blockIdx.x * MT + w) * TT + t) * II;
            float* dst = xs + w * XR;
            #pragma unroll
            for (int i = 0; i < 5; ++i) dst[lane + i * 64] = src[lane + i * 64];
            __syncthreads();
        }
        const int dt = t & 63;
        const int wp = t & 1, rp = wp ^ 1;
        const int off0 = b * HR + q * 8, off1 = off0 + 32;

        // ================= Layer 1 =================
        floatx4 accA, accB = {0.f, 0.f, 0.f, 0.f};
        {
            const float* xv = xs + b * XR + dt * II;
            const float x0 = xv[0], x1 = xv[1], x2 = xv[2], x3 = xv[3], x4 = xv[4];
            #pragma unroll
            for (int r = 0; r < 4; ++r)
                accA[r] = bias1[r] + Wx[r][0]*x0 + Wx[r][1]*x1 + Wx[r][2]*x2
                                   + Wx[r][3]*x3 + Wx[r][4]*x4;
        }
        {
            short8 Bh0 = *(const short8*)(&h1hi[rp][off0]);
            short8 Bl0 = *(const short8*)(&h1lo[rp][off0]);
            short8 Bh1 = *(const short8*)(&h1hi[rp][off1]);
            short8 Bl1 = *(const short8*)(&h1lo[rp][off1]);
            accA = MFMA(A1h[0], Bh0, accA);
            accA = MFMA(A1h[0], Bl0, accA);
            accA = MFMA(A1l[0], Bh0, accA);
            accB = MFMA(A1h[1], Bh1, accB);
            accB = MFMA(A1h[1], Bl1, accB);
            accB = MFMA(A1l[1], Bh1, accB);
        }
        {
            const float gi = fsig  (accA[0] + accB[0]);
            const float gf = fsig  (accA[1] + accB[1]);
            const float gz = ftanhf(accA[2] + accB[2]);
            const float go = fsig  (accA[3] + accB[3]);
            c1 = gf * c1 + gi * gz;
            const float h = go * ftanhf(c1);
            HiLo s = split2(h);
            h1hi[wp][hw_off] = (unsigned short)s.hi;
            h1lo[wp][hw_off] = (unsigned short)s.lo;
        }
        __syncthreads();

        // ================= Layer 2 =================
        #pragma unroll
        for (int r = 0; r < 4; ++r) { accA[r] = bias2[r]; accB[r] = 0.f; }
        {
            short8 Bh0 = *(const short8*)(&h1hi[wp][off0]);
            short8 Bl0 = *(const short8*)(&h1lo[wp][off0]);
            short8 Bh1 = *(const short8*)(&h1hi[wp][off1]);
            short8 Bl1 = *(const short8*)(&h1lo[wp][off1]);
            accA = MFMA(A2h[0], Bh0, accA);
            accA = MFMA(A2h[0], Bl0, accA);
            accA = MFMA(A2l[0], Bh0, accA);
            accA = MFMA(A2h[1], Bh1, accA);
            accA = MFMA(A2h[1], Bl1, accA);
            accA = MFMA(A2l[1], Bh1, accA);
        }
        {
            short8 Dh0 = *(const short8*)(&h2hi[rp][off0]);
            short8 Dl0 = *(const short8*)(&h2lo[rp][off0]);
            short8 Dh1 = *(const short8*)(&h2hi[rp][off1]);
            short8 Dl1 = *(const short8*)(&h2lo[rp][off1]);
            accB = MFMA(A2h[2], Dh0, accB);
            accB = MFMA(A2h[2], Dl0, accB);
            accB = MFMA(A2l[2], Dh0, accB);
            accB = MFMA(A2h[3], Dh1, accB);
            accB = MFMA(A2h[3], Dl1, accB);
            accB = MFMA(A2l[3], Dh1, accB);
        }
        {
            const float gi = fsig  (accA[0] + accB[0]);
            const float gf = fsig  (accA[1] + accB[1]);
            const float gz = ftanhf(accA[2] + accB[2]);
            const float go = fsig  (accA[3] + accB[3]);
            c2 = gf * c2 + gi * gz;
            const float h = go * ftanhf(c2);
            HiLo s = split2(h);
            h2hi[wp][hw_off] = (unsigned short)s.hi;
            h2lo[wp][hw_off] = (unsigned short)s.lo;
            if (t == TT - 1) h2f[b * HF + jmine] = h;
        }
        __syncthreads();
    }

    // ================= FC epilogue =================
    if (tid < MT * OO) {
        const int bb = tid / OO, o = tid - bb * OO;
        float acc = bfc[o];
        const float* wr = Wfc + o * HH;
        const float* hr = h2f + bb * HF;
        #pragma unroll
        for (int j = 0; j < HH; ++j) acc += wr[j] * hr[j];
        out[((size_t)blockIdx.x * MT + bb) * OO + o] = acc;
    }
}

extern "C" void kernel_launch(void* const* d_in, const int* in_sizes, int n_in,
                              void* d_out, int out_size, void* d_ws, size_t ws_size,
                              hipStream_t stream) {
    const float* x    = (const float*)d_in[0];
    const float* Wih0 = (const float*)d_in[1];
    const float* Whh0 = (const float*)d_in[2];
    const float* bih0 = (const float*)d_in[3];
    const float* bhh0 = (const float*)d_in[4];
    const float* Wih1 = (const float*)d_in[5];
    const float* Whh1 = (const float*)d_in[6];
    const float* bih1 = (const float*)d_in[7];
    const float* bhh1 = (const float*)d_in[8];
    const float* Wfc  = (const float*)d_in[9];
    const float* bfc  = (const float*)d_in[10];
    float* out = (float*)d_out;

    dim3 grid(4096 / MT), block(NTHR);
    lstm_mfma2<<<grid, block, 0, stream>>>(x, Wih0, Whh0, bih0, bhh0,
                                           Wih1, Whh1, bih1, bhh1,
                                           Wfc, bfc, out);
}